// Round 4
// baseline (4303.394 us; speedup 1.0000x reference)
//
#include <hip/hip_runtime.h>

typedef unsigned short u16;
typedef unsigned int u32;
typedef __attribute__((ext_vector_type(8))) short short8;
typedef __attribute__((ext_vector_type(4))) float floatx4;
typedef __attribute__((ext_vector_type(4))) u32 uintx4;

#define LSEQ 4096
#define TOKD 16384            // tokens per direction (4 batches x 4096)

__device__ __forceinline__ float bf2f(u16 u) {
    u32 v = ((u32)u) << 16; float f; __builtin_memcpy(&f, &v, 4); return f;
}
__device__ __forceinline__ u16 f2bf(float f) {
    u32 v; __builtin_memcpy(&v, &f, 4);
    u32 r = v + 0x7fffu + ((v >> 16) & 1u);
    return (u16)(r >> 16);
}
__device__ __forceinline__ float siluf(float v) { return v / (1.f + __expf(-v)); }

// position in original image for token t of direction dir
__device__ __forceinline__ int dir_pos(int dir, int t) {
    if (dir == 0) return t;
    if (dir == 1) { int i = t >> 6, j = t & 63; return ((63 - j) << 6) | i; }
    if (dir == 2) return 4095 - t;
    int t2 = 4095 - t; int i = t2 >> 6, j = t2 & 63; return ((63 - j) << 6) | i;
}

// ---------------------------------------------------------------------------
// dtype detector: bf16-decode of fp32 mantissa halves is log-uniform (~6% in
// (1e-3,100)); genuine N(0,1) bf16 is ~99.9% in-range. flag=1 -> fp32 inputs.
// ---------------------------------------------------------------------------
__global__ __launch_bounds__(256)
void detect_k(const u16* __restrict__ xr, int* __restrict__ flag)
{
    int tid = threadIdx.x;
    int cnt = 0;
    for (int i = tid; i < 4096; i += 256) {
        float a = fabsf(bf2f(xr[i]));
        if (a > 0.001f && a < 100.f) cnt++;
    }
#pragma unroll
    for (int o = 1; o < 64; o <<= 1) cnt += __shfl_xor(cnt, o);
    __shared__ int red[4];
    if ((tid & 63) == 0) red[tid >> 6] = cnt;
    __syncthreads();
    if (tid == 0) flag[0] = ((red[0] + red[1] + red[2] + red[3]) < 3277) ? 1 : 0;
}

// convert one input to canonical bf16 (copy if already bf16)
__global__ __launch_bounds__(256)
void convert_k(const void* __restrict__ src, u16* __restrict__ dst, int n,
               const int* __restrict__ flag)
{
    bool isf = flag[0] != 0;
    int stride = gridDim.x * 256;
    for (int i = blockIdx.x * 256 + threadIdx.x; i < n; i += stride) {
        dst[i] = isf ? f2bf(((const float*)src)[i]) : ((const u16*)src)[i];
    }
}

// ---------------------------------------------------------------------------
// bf16 MFMA GEMM core: C(M,N) = A(M,K) @ Bw(N,K)^T, tile 64x64, 256 thr.
// EPI: 1 = fp32 store w/ col guard (x_proj N=48)
//      3 = store + bias + residual (final block out; fp32 or bf16 per flag)
//      4 = bf16 store of silu(v)   (z half)
//      5 = fp32 STORE to permuted row (out-proj, dir 0)
//      6 = fp32 ADD   to permuted row (out-proj, dirs 1-3)
// GATHER: A rows gathered (direction dir)
// ---------------------------------------------------------------------------
template<int EPI, bool GATHER>
__global__ __launch_bounds__(256)
void gemm_k(const u16* __restrict__ A, const u16* __restrict__ Bw,
            int M, int N, int K, int dir,
            float* __restrict__ outF, u16* __restrict__ out0,
            const u16* __restrict__ bias, const u16* __restrict__ resid,
            const int* __restrict__ flag)
{
    __shared__ __align__(16) u16 As[64][40];
    __shared__ __align__(16) u16 Bs[64][40];

    int tid = threadIdx.x;
    int ntile = blockIdx.x, mtile = blockIdx.y;
    int lr = tid >> 2;
    int lc = (tid & 3) << 3;

    const u16* arow;
    {
        int g = mtile * 64 + lr;
        if (GATHER) {
            int b = g >> 12, t = g & 4095;
            arow = A + (size_t)(b * 4096 + dir_pos(dir, t)) * K;
        } else {
            arow = A + (size_t)g * K;
        }
    }
    int bn = ntile * 64 + lr;
    const u16* brow = (bn < N) ? (Bw + (size_t)bn * K) : nullptr;

    floatx4 acc[4];
#pragma unroll
    for (int i = 0; i < 4; i++) acc[i] = (floatx4)0.f;

    int lane = tid & 63, wv = tid >> 6;
    int lm = lane & 15;
    int kq = (lane >> 4) << 3;

    for (int k0 = 0; k0 < K; k0 += 32) {
        __syncthreads();
        uintx4 av = *(const uintx4*)(arow + k0 + lc);
        uintx4 bv = {0u, 0u, 0u, 0u};
        if (brow) bv = *(const uintx4*)(brow + k0 + lc);
        *(uintx4*)(&As[lr][lc]) = av;
        *(uintx4*)(&Bs[lr][lc]) = bv;
        __syncthreads();
        short8 af = *(const short8*)(&As[wv * 16 + lm][kq]);
#pragma unroll
        for (int nt = 0; nt < 4; nt++) {
            short8 bf = *(const short8*)(&Bs[nt * 16 + lm][kq]);
            acc[nt] = __builtin_amdgcn_mfma_f32_16x16x32_bf16(af, bf, acc[nt], 0, 0, 0);
        }
    }

    bool isf = (EPI == 3) ? (flag[0] != 0) : false;
    int colb = lane & 15;
    int rowb = (lane >> 4) << 2;
#pragma unroll
    for (int nt = 0; nt < 4; nt++) {
#pragma unroll
        for (int r = 0; r < 4; r++) {
            int mg = mtile * 64 + wv * 16 + rowb + r;
            int cg = ntile * 64 + nt * 16 + colb;
            float v = acc[nt][r];
            if (EPI == 1) {
                if (cg < N) outF[(size_t)mg * N + cg] = v;
            } else if (EPI == 3) {
                size_t idx = (size_t)mg * N + cg;
                float rr = v + bf2f(bias[cg]) + bf2f(resid[idx]);
                if (isf) outF[idx] = rr;
                else     out0[idx] = f2bf(rr);
            } else if (EPI == 4) {
                out0[(size_t)mg * N + cg] = f2bf(siluf(v));
            } else {   // 5 / 6: permuted-row fp32 accumulate
                int b = mg >> 12, t = mg & 4095;
                size_t idx = (size_t)(b * 4096 + dir_pos(dir, t)) * N + cg;
                if (EPI == 5) outF[idx] = v;
                else          outF[idx] += v;
            }
        }
    }
}

// ---------------------------------------------------------------------------
// fused in_proj(xc half) GEMM + depthwise causal conv(k=4) + bias + SiLU.
// tile 64 tokens x 64 channels; 3-token halo recomputed on VALU.
// writes xcv (TOKD x 512 bf16) in DIRECTIONAL token order.
// ---------------------------------------------------------------------------
__global__ __launch_bounds__(256)
void gemmconv_k(const u16* __restrict__ x, const u16* __restrict__ Wc,
                const u16* __restrict__ cw, const u16* __restrict__ cb,
                u16* __restrict__ xcv, int dir)
{
    __shared__ __align__(16) u16 As[64][40];
    __shared__ __align__(16) u16 Bs[64][40];
    __shared__ float xcS[67][68];   // rows 0..2 = halo (tokens g0-3..g0-1)

    int tid = threadIdx.x;
    int ntile = blockIdx.x, mtile = blockIdx.y;
    int n0 = ntile * 64;
    int g0 = mtile * 64;
    int bb = g0 >> 12;
    int lr = tid >> 2;
    int lc = (tid & 3) << 3;

    const u16* arow = x + (size_t)(bb * 4096 + dir_pos(dir, (g0 + lr) & 4095)) * 256;
    const u16* brow = Wc + (size_t)(n0 + lr) * 256;

    floatx4 acc[4];
#pragma unroll
    for (int i = 0; i < 4; i++) acc[i] = (floatx4)0.f;

    int lane = tid & 63, wv = tid >> 6;
    int lm = lane & 15;
    int kq = (lane >> 4) << 3;

    for (int k0 = 0; k0 < 256; k0 += 32) {
        __syncthreads();
        uintx4 av = *(const uintx4*)(arow + k0 + lc);
        uintx4 bv = *(const uintx4*)(brow + k0 + lc);
        *(uintx4*)(&As[lr][lc]) = av;
        *(uintx4*)(&Bs[lr][lc]) = bv;
        __syncthreads();
        short8 af = *(const short8*)(&As[wv * 16 + lm][kq]);
#pragma unroll
        for (int nt = 0; nt < 4; nt++) {
            short8 bf = *(const short8*)(&Bs[nt * 16 + lm][kq]);
            acc[nt] = __builtin_amdgcn_mfma_f32_16x16x32_bf16(af, bf, acc[nt], 0, 0, 0);
        }
    }

    __syncthreads();
    {
        int colb = lane & 15;
        int rowb = (lane >> 4) << 2;
#pragma unroll
        for (int nt = 0; nt < 4; nt++)
#pragma unroll
            for (int r = 0; r < 4; r++)
                xcS[3 + wv * 16 + rowb + r][nt * 16 + colb] = acc[nt][r];
    }
    if (tid < 192) {   // halo rows: in-seq tokens g0-3..g0-1, zero before seq start
        int hr = tid >> 6, hc = tid & 63;
        int th = (g0 & 4095) - 3 + hr;
        float a = 0.f;
        if (th >= 0) {
            const u16* xr = x + (size_t)(bb * 4096 + dir_pos(dir, th)) * 256;
            const u16* wr = Wc + (size_t)(n0 + hc) * 256;
            for (int k = 0; k < 256; k += 8) {
                uintx4 xv = *(const uintx4*)(xr + k);
                uintx4 wv4 = *(const uintx4*)(wr + k);
                const u16* pxv = (const u16*)&xv;
                const u16* pwv = (const u16*)&wv4;
#pragma unroll
                for (int i = 0; i < 8; i++) a += bf2f(pxv[i]) * bf2f(pwv[i]);
            }
        }
        xcS[hr][hc] = a;
    }
    __syncthreads();
    for (int e = tid; e < 4096; e += 256) {
        int tr = e >> 6, c = e & 63;
        float s = bf2f(cb[n0 + c]);
#pragma unroll
        for (int k = 0; k < 4; k++)
            s += bf2f(cw[(n0 + c) * 4 + k]) * xcS[tr + k][c];
        xcv[(size_t)(g0 + tr) * 512 + n0 + c] = f2bf(siluf(s));
    }
}

// ---------------------------------------------------------------------------
// selective scan w/ fused dt-projection + D-skip + silu(z) gating.
// grid (32 d-groups, 4 seqs); 256 thr = 16 ch x 16 states. y in place (xcv).
// ---------------------------------------------------------------------------
__global__ __launch_bounds__(256)
void scan_k(u16* __restrict__ xcv, const u16* __restrict__ zsil,
            const float* __restrict__ xdbl,
            const u16* __restrict__ dtW, const u16* __restrict__ dtB,
            const u16* __restrict__ A_log, const u16* __restrict__ D_skip)
{
    int d0 = blockIdx.x * 16;
    int tid = threadIdx.x;
    int s = tid & 15, dl = tid >> 4;
    float Aval = -__expf(bf2f(A_log[(d0 + dl) * 16 + s]));
    float Dv = bf2f(D_skip[d0 + dl]);

    __shared__ float dtlS[64][16], xS[64][16], zS[64][16], BS[64][16], CS[64][16];
    __shared__ float dtS[64][16], yS[64][16];
    __shared__ float WdS[16][16], bDS[16];

    {
        int r = tid & 15, dd = tid >> 4;
        WdS[dd][r] = bf2f(dtW[(d0 + dd) * 16 + r]);
        if (tid < 16) bDS[tid] = bf2f(dtB[d0 + tid]);
    }

    float h = 0.f;
    const int base_m = blockIdx.y * 4096;
    int ld_tt = tid >> 2;
    int ld_c4 = (tid & 3) * 4;

    for (int tc = 0; tc < 4096; tc += 64) {
        __syncthreads();
        {
            int m = base_m + tc + ld_tt;
            const u16* px = xcv + (size_t)m * 512 + d0 + ld_c4;
            const u16* pz = zsil + (size_t)m * 512 + d0 + ld_c4;
#pragma unroll
            for (int r = 0; r < 4; r++) {
                xS[ld_tt][ld_c4 + r] = bf2f(px[r]);
                zS[ld_tt][ld_c4 + r] = bf2f(pz[r]);
            }
            const float* pl = xdbl + (size_t)m * 48;
#pragma unroll
            for (int r = 0; r < 4; r++) {
                dtlS[ld_tt][ld_c4 + r] = pl[ld_c4 + r];
                BS[ld_tt][ld_c4 + r]   = pl[16 + ld_c4 + r];
                CS[ld_tt][ld_c4 + r]   = pl[32 + ld_c4 + r];
            }
        }
        __syncthreads();
        {
            int tt = tid >> 2;
            int j0 = (tid & 3) * 4;
#pragma unroll
            for (int j = 0; j < 4; j++) {
                int dd = j0 + j;
                float a = bDS[dd];
#pragma unroll
                for (int r = 0; r < 16; r++) a = fmaf(dtlS[tt][r], WdS[dd][r], a);
                dtS[tt][dd] = (a > 20.f) ? a : log1pf(__expf(a));
            }
        }
        __syncthreads();
        for (int tt = 0; tt < 64; tt++) {
            float dtv = dtS[tt][dl];
            float xv  = xS[tt][dl];
            float a = __expf(dtv * Aval);
            h = fmaf(a, h, dtv * xv * BS[tt][s]);
            float yc = h * CS[tt][s];
            yc += __shfl_xor(yc, 1);
            yc += __shfl_xor(yc, 2);
            yc += __shfl_xor(yc, 4);
            yc += __shfl_xor(yc, 8);
            if (s == 0) yS[tt][dl] = (yc + Dv * xv) * zS[tt][dl];
        }
        __syncthreads();
        {
            int m = base_m + tc + ld_tt;
            u16* py = xcv + (size_t)m * 512 + d0 + ld_c4;
            u32 a0 = (u32)f2bf(yS[ld_tt][ld_c4 + 0]) | ((u32)f2bf(yS[ld_tt][ld_c4 + 1]) << 16);
            u32 a1 = (u32)f2bf(yS[ld_tt][ld_c4 + 2]) | ((u32)f2bf(yS[ld_tt][ld_c4 + 3]) << 16);
            uint2 pk; pk.x = a0; pk.y = a1;
            *(uint2*)py = pk;
        }
    }
}

// ---------------------------------------------------------------------------
// LayerNorm over combined fp32 accumulator
// ---------------------------------------------------------------------------
__global__ __launch_bounds__(256)
void ln_k(const float* __restrict__ accF, const u16* __restrict__ g,
          const u16* __restrict__ bt, u16* __restrict__ lnout)
{
    int m = blockIdx.x;
    int c = threadIdx.x;
    float v = accF[(size_t)m * 256 + c];
    v = fminf(fmaxf(v, -1e4f), 1e4f);

    float s1 = v, s2 = v * v;
#pragma unroll
    for (int o = 1; o < 64; o <<= 1) { s1 += __shfl_xor(s1, o); s2 += __shfl_xor(s2, o); }
    __shared__ float red[8];
    int wv = threadIdx.x >> 6;
    if ((threadIdx.x & 63) == 0) { red[wv] = s1; red[4 + wv] = s2; }
    __syncthreads();
    s1 = red[0] + red[1] + red[2] + red[3];
    s2 = red[4] + red[5] + red[6] + red[7];
    float mu = s1 * (1.f / 256.f);
    float var = s2 * (1.f / 256.f) - mu * mu;
    float rs = rsqrtf(fmaxf(var, 0.f) + 1e-5f);
    float o = (v - mu) * rs * bf2f(g[c]) + bf2f(bt[c]);
    lnout[(size_t)m * 256 + c] = f2bf(o);
}

// ---------------------------------------------------------------------------
extern "C" void kernel_launch(void* const* d_in, const int* in_sizes, int n_in,
                              void* d_out, int out_size, void* d_ws, size_t ws_size,
                              hipStream_t stream)
{
    char* w = (char*)d_ws;
    int* flag = (int*)w;
    size_t cur = 256;
    auto carve = [&](size_t bytes) { void* p = w + cur; cur = (cur + bytes + 255) & ~(size_t)255; return p; };

    // canonical bf16 inputs
    static const int sizes[14] = {
        4194304, 262144, 2048, 512, 24576, 8192, 512, 8192, 512, 131072, 256, 256, 65536, 256
    };
    u16* cin[14];
    for (int i = 0; i < 14; i++) cin[i] = (u16*)carve((size_t)sizes[i] * 2);

    float* accF = (float*)carve(16777216);      // fp32 combine accumulator
    u16*  xcv  = (u16*)carve(16777216);         // per-direction xc/conv/y
    u16*  zbuf = (u16*)carve(16777216);         // per-direction silu(z)
    float* xdbl = (float*)carve(3145728);       // per-direction fp32 (dt_low|B|C)
    u16*  lnb  = xcv;                           // reuse after last direction

    const u16* x          = cin[0];
    const u16* in_proj_w  = cin[1];
    const u16* conv_w     = cin[2];
    const u16* conv_b     = cin[3];
    const u16* x_proj_w   = cin[4];
    const u16* dt_proj_w  = cin[5];
    const u16* dt_proj_b  = cin[6];
    const u16* A_log      = cin[7];
    const u16* D_skip     = cin[8];
    const u16* mamba_out_w= cin[9];
    const u16* ln_g       = cin[10];
    const u16* ln_b       = cin[11];
    const u16* blk_out_w  = cin[12];
    const u16* blk_out_b  = cin[13];

    // 0. dtype detect + canonicalize all inputs to bf16
    detect_k<<<dim3(1), 256, 0, stream>>>((const u16*)d_in[0], flag);
    for (int i = 0; i < 14; i++) {
        int n = sizes[i];
        int blocks = (n + 2047) / 2048; if (blocks < 1) blocks = 1;
        convert_k<<<dim3(blocks), 256, 0, stream>>>(d_in[i], cin[i], n, flag);
    }

    for (int dir = 0; dir < 4; dir++) {
        // 1. in_proj xc-half + conv + silu -> xcv
        gemmconv_k<<<dim3(8, 256), 256, 0, stream>>>(
            x, in_proj_w, conv_w, conv_b, xcv, dir);
        // 2. in_proj z-half + silu -> zbuf
        gemm_k<4, true><<<dim3(8, 256), 256, 0, stream>>>(
            x, in_proj_w + 512 * 256, TOKD, 512, 256, dir, nullptr, zbuf,
            nullptr, nullptr, nullptr);
        // 3. x_proj -> xdbl (fp32)
        gemm_k<1, false><<<dim3(1, 256), 256, 0, stream>>>(
            xcv, x_proj_w, TOKD, 48, 512, dir, xdbl, nullptr, nullptr, nullptr, nullptr);
        // 4. selective scan (dt fused) + gating, in place over xcv
        scan_k<<<dim3(32, 4), 256, 0, stream>>>(
            xcv, zbuf, xdbl, dt_proj_w, dt_proj_b, A_log, D_skip);
        // 5. out projection, permuted rows into fp32 accumulator
        if (dir == 0)
            gemm_k<5, false><<<dim3(4, 256), 256, 0, stream>>>(
                xcv, mamba_out_w, TOKD, 256, 512, dir, accF, nullptr, nullptr, nullptr, nullptr);
        else
            gemm_k<6, false><<<dim3(4, 256), 256, 0, stream>>>(
                xcv, mamba_out_w, TOKD, 256, 512, dir, accF, nullptr, nullptr, nullptr, nullptr);
    }
    // 6. LayerNorm over combined accumulator
    ln_k<<<dim3(16384), 256, 0, stream>>>(accF, ln_g, ln_b, lnb);
    // 7. final projection + bias + residual (output dtype per flag)
    gemm_k<3, false><<<dim3(4, 256), 256, 0, stream>>>(
        lnb, blk_out_w, 16384, 256, 256, 0, (float*)d_out, (u16*)d_out,
        blk_out_b, x, flag);
}

// Round 5
// 1449.241 us; speedup vs baseline: 2.9694x; 2.9694x over previous
//
#include <hip/hip_runtime.h>

typedef unsigned short u16;
typedef unsigned int u32;
typedef __attribute__((ext_vector_type(8))) short short8;
typedef __attribute__((ext_vector_type(4))) float floatx4;
typedef __attribute__((ext_vector_type(4))) u32 uintx4;

#define LSEQ 4096
#define TOKD 16384            // tokens per direction (4 batches x 4096)

__device__ __forceinline__ float bf2f(u16 u) {
    u32 v = ((u32)u) << 16; float f; __builtin_memcpy(&f, &v, 4); return f;
}
__device__ __forceinline__ u16 f2bf(float f) {
    u32 v; __builtin_memcpy(&v, &f, 4);
    u32 r = v + 0x7fffu + ((v >> 16) & 1u);
    return (u16)(r >> 16);
}
__device__ __forceinline__ float siluf(float v) { return v / (1.f + __expf(-v)); }

// position in original image for token t of direction dir
__device__ __forceinline__ int dir_pos(int dir, int t) {
    if (dir == 0) return t;
    if (dir == 1) { int i = t >> 6, j = t & 63; return ((63 - j) << 6) | i; }
    if (dir == 2) return 4095 - t;
    int t2 = 4095 - t; int i = t2 >> 6, j = t2 & 63; return ((63 - j) << 6) | i;
}

// ---------------------------------------------------------------------------
// dtype detector (flag=1 -> fp32 inputs). Confirmed fp32 in round 4; kept for
// robustness (costs ~2 us).
// ---------------------------------------------------------------------------
__global__ __launch_bounds__(256)
void detect_k(const u16* __restrict__ xr, int* __restrict__ flag)
{
    int tid = threadIdx.x;
    int cnt = 0;
    for (int i = tid; i < 4096; i += 256) {
        float a = fabsf(bf2f(xr[i]));
        if (a > 0.001f && a < 100.f) cnt++;
    }
#pragma unroll
    for (int o = 1; o < 64; o <<= 1) cnt += __shfl_xor(cnt, o);
    __shared__ int red[4];
    if ((tid & 63) == 0) red[tid >> 6] = cnt;
    __syncthreads();
    if (tid == 0) flag[0] = ((red[0] + red[1] + red[2] + red[3]) < 3277) ? 1 : 0;
}

__global__ __launch_bounds__(256)
void convert_k(const void* __restrict__ src, u16* __restrict__ dst, int n,
               const int* __restrict__ flag)
{
    bool isf = flag[0] != 0;
    int stride = gridDim.x * 256;
    for (int i = blockIdx.x * 256 + threadIdx.x; i < n; i += stride) {
        dst[i] = isf ? f2bf(((const float*)src)[i]) : ((const u16*)src)[i];
    }
}

// ---------------------------------------------------------------------------
// bf16 MFMA GEMM core: C(M,N) = A(M,K) @ Bw(N,K)^T, tile 64x64, 256 thr.
// EPI: 1 = fp32 store w/ col guard (x_proj N=48)
//      3 = store + bias + residual (final block out; fp32 or bf16 per flag)
//      4 = bf16 store of silu(v)   (z half)
//      5 = fp32 STORE to permuted row (out-proj, dir 0)
//      6 = fp32 ADD   to permuted row (out-proj, dirs 1-3)
// ---------------------------------------------------------------------------
template<int EPI, bool GATHER>
__global__ __launch_bounds__(256)
void gemm_k(const u16* __restrict__ A, const u16* __restrict__ Bw,
            int M, int N, int K, int dir,
            float* __restrict__ outF, u16* __restrict__ out0,
            const u16* __restrict__ bias, const u16* __restrict__ resid,
            const int* __restrict__ flag)
{
    __shared__ __align__(16) u16 As[64][40];
    __shared__ __align__(16) u16 Bs[64][40];

    int tid = threadIdx.x;
    int ntile = blockIdx.x, mtile = blockIdx.y;
    int lr = tid >> 2;
    int lc = (tid & 3) << 3;

    const u16* arow;
    {
        int g = mtile * 64 + lr;
        if (GATHER) {
            int b = g >> 12, t = g & 4095;
            arow = A + (size_t)(b * 4096 + dir_pos(dir, t)) * K;
        } else {
            arow = A + (size_t)g * K;
        }
    }
    int bn = ntile * 64 + lr;
    const u16* brow = (bn < N) ? (Bw + (size_t)bn * K) : nullptr;

    floatx4 acc[4];
#pragma unroll
    for (int i = 0; i < 4; i++) acc[i] = (floatx4)0.f;

    int lane = tid & 63, wv = tid >> 6;
    int lm = lane & 15;
    int kq = (lane >> 4) << 3;

    for (int k0 = 0; k0 < K; k0 += 32) {
        __syncthreads();
        uintx4 av = *(const uintx4*)(arow + k0 + lc);
        uintx4 bv = {0u, 0u, 0u, 0u};
        if (brow) bv = *(const uintx4*)(brow + k0 + lc);
        *(uintx4*)(&As[lr][lc]) = av;
        *(uintx4*)(&Bs[lr][lc]) = bv;
        __syncthreads();
        short8 af = *(const short8*)(&As[wv * 16 + lm][kq]);
#pragma unroll
        for (int nt = 0; nt < 4; nt++) {
            short8 bf = *(const short8*)(&Bs[nt * 16 + lm][kq]);
            acc[nt] = __builtin_amdgcn_mfma_f32_16x16x32_bf16(af, bf, acc[nt], 0, 0, 0);
        }
    }

    bool isf = (EPI == 3) ? (flag[0] != 0) : false;
    int colb = lane & 15;
    int rowb = (lane >> 4) << 2;
#pragma unroll
    for (int nt = 0; nt < 4; nt++) {
#pragma unroll
        for (int r = 0; r < 4; r++) {
            int mg = mtile * 64 + wv * 16 + rowb + r;
            int cg = ntile * 64 + nt * 16 + colb;
            float v = acc[nt][r];
            if (EPI == 1) {
                if (cg < N) outF[(size_t)mg * N + cg] = v;
            } else if (EPI == 3) {
                size_t idx = (size_t)mg * N + cg;
                float rr = v + bf2f(bias[cg]) + bf2f(resid[idx]);
                if (isf) outF[idx] = rr;
                else     out0[idx] = f2bf(rr);
            } else if (EPI == 4) {
                out0[(size_t)mg * N + cg] = f2bf(siluf(v));
            } else {   // 5 / 6: permuted-row fp32 accumulate
                int b = mg >> 12, t = mg & 4095;
                size_t idx = (size_t)(b * 4096 + dir_pos(dir, t)) * N + cg;
                if (EPI == 5) outF[idx] = v;
                else          outF[idx] += v;
            }
        }
    }
}

// ---------------------------------------------------------------------------
// fused in_proj(xc half) GEMM + depthwise causal conv(k=4) + bias + SiLU.
// ---------------------------------------------------------------------------
__global__ __launch_bounds__(256)
void gemmconv_k(const u16* __restrict__ x, const u16* __restrict__ Wc,
                const u16* __restrict__ cw, const u16* __restrict__ cb,
                u16* __restrict__ xcv, int dir)
{
    __shared__ __align__(16) u16 As[64][40];
    __shared__ __align__(16) u16 Bs[64][40];
    __shared__ float xcS[67][68];   // rows 0..2 = halo (tokens g0-3..g0-1)

    int tid = threadIdx.x;
    int ntile = blockIdx.x, mtile = blockIdx.y;
    int n0 = ntile * 64;
    int g0 = mtile * 64;
    int bb = g0 >> 12;
    int lr = tid >> 2;
    int lc = (tid & 3) << 3;

    const u16* arow = x + (size_t)(bb * 4096 + dir_pos(dir, (g0 + lr) & 4095)) * 256;
    const u16* brow = Wc + (size_t)(n0 + lr) * 256;

    floatx4 acc[4];
#pragma unroll
    for (int i = 0; i < 4; i++) acc[i] = (floatx4)0.f;

    int lane = tid & 63, wv = tid >> 6;
    int lm = lane & 15;
    int kq = (lane >> 4) << 3;

    for (int k0 = 0; k0 < 256; k0 += 32) {
        __syncthreads();
        uintx4 av = *(const uintx4*)(arow + k0 + lc);
        uintx4 bv = *(const uintx4*)(brow + k0 + lc);
        *(uintx4*)(&As[lr][lc]) = av;
        *(uintx4*)(&Bs[lr][lc]) = bv;
        __syncthreads();
        short8 af = *(const short8*)(&As[wv * 16 + lm][kq]);
#pragma unroll
        for (int nt = 0; nt < 4; nt++) {
            short8 bf = *(const short8*)(&Bs[nt * 16 + lm][kq]);
            acc[nt] = __builtin_amdgcn_mfma_f32_16x16x32_bf16(af, bf, acc[nt], 0, 0, 0);
        }
    }

    __syncthreads();
    {
        int colb = lane & 15;
        int rowb = (lane >> 4) << 2;
#pragma unroll
        for (int nt = 0; nt < 4; nt++)
#pragma unroll
            for (int r = 0; r < 4; r++)
                xcS[3 + wv * 16 + rowb + r][nt * 16 + colb] = acc[nt][r];
    }
    if (tid < 192) {   // halo rows
        int hr = tid >> 6, hc = tid & 63;
        int th = (g0 & 4095) - 3 + hr;
        float a = 0.f;
        if (th >= 0) {
            const u16* xr = x + (size_t)(bb * 4096 + dir_pos(dir, th)) * 256;
            const u16* wr = Wc + (size_t)(n0 + hc) * 256;
            for (int k = 0; k < 256; k += 8) {
                uintx4 xv = *(const uintx4*)(xr + k);
                uintx4 wv4 = *(const uintx4*)(wr + k);
                const u16* pxv = (const u16*)&xv;
                const u16* pwv = (const u16*)&wv4;
#pragma unroll
                for (int i = 0; i < 8; i++) a += bf2f(pxv[i]) * bf2f(pwv[i]);
            }
        }
        xcS[hr][hc] = a;
    }
    __syncthreads();
    for (int e = tid; e < 4096; e += 256) {
        int tr = e >> 6, c = e & 63;
        float s = bf2f(cb[n0 + c]);
#pragma unroll
        for (int k = 0; k < 4; k++)
            s += bf2f(cw[(n0 + c) * 4 + k]) * xcS[tr + k][c];
        xcv[(size_t)(g0 + tr) * 512 + n0 + c] = f2bf(siluf(s));
    }
}

// ===========================================================================
// Two-level chunked selective scan.
// h(t) = a(t) h(t-1) + b(t);  a = exp(dt*A), b = dt*x*B.
// Groups of T=64 tokens; G=64 groups per 4096-token sequence.
//   S1: per group, seed h=0 -> h_end and decay product A_g   (8192 blocks)
//   S2: serial combine over groups -> h_in(g), in place      (128 blocks)
//   S3: re-run group seeded with h_in(g), emit gated y       (8192 blocks)
// state layout: idx = ((seq*64+g)*512 + d)*16 + s
// ===========================================================================
__global__ __launch_bounds__(256)
void scan1_k(const u16* __restrict__ xcv, const float* __restrict__ xdbl,
             const u16* __restrict__ dtW, const u16* __restrict__ dtB,
             const u16* __restrict__ A_log,
             float* __restrict__ hend, float* __restrict__ Ag)
{
    int d0 = blockIdx.x * 16;
    int g  = blockIdx.y;
    int seq = blockIdx.z;
    int tid = threadIdx.x;
    int s = tid & 15, dl = tid >> 4;
    float Aval = -__expf(bf2f(A_log[(d0 + dl) * 16 + s]));

    __shared__ float dtlS[64][16], xS[64][16], BS[64][16], dtS[64][16];
    __shared__ float WdS[16][16], bDS[16];
    {
        int r = tid & 15, dd = tid >> 4;
        WdS[dd][r] = bf2f(dtW[(d0 + dd) * 16 + r]);
        if (tid < 16) bDS[tid] = bf2f(dtB[d0 + tid]);
    }

    int ld_tt = tid >> 2;
    int ld_c4 = (tid & 3) * 4;
    {
        int m = seq * 4096 + g * 64 + ld_tt;
        const u16* px = xcv + (size_t)m * 512 + d0 + ld_c4;
#pragma unroll
        for (int r = 0; r < 4; r++) xS[ld_tt][ld_c4 + r] = bf2f(px[r]);
        const float* pl = xdbl + (size_t)m * 48;
#pragma unroll
        for (int r = 0; r < 4; r++) {
            dtlS[ld_tt][ld_c4 + r] = pl[ld_c4 + r];
            BS[ld_tt][ld_c4 + r]   = pl[16 + ld_c4 + r];
        }
    }
    __syncthreads();
    {   // dt = softplus(dt_low @ Wd^T + b)
        int tt = tid >> 2;
        int j0 = (tid & 3) * 4;
#pragma unroll
        for (int j = 0; j < 4; j++) {
            int dd = j0 + j;
            float a = bDS[dd];
#pragma unroll
            for (int r = 0; r < 16; r++) a = fmaf(dtlS[tt][r], WdS[dd][r], a);
            dtS[tt][dd] = (a > 20.f) ? a : log1pf(__expf(a));
        }
    }
    __syncthreads();

    float h = 0.f, P = 1.f;
#pragma unroll 8
    for (int tt = 0; tt < 64; tt++) {
        float dtv = dtS[tt][dl];
        float a = __expf(dtv * Aval);
        h = fmaf(a, h, dtv * xS[tt][dl] * BS[tt][s]);
        P *= a;
    }
    size_t idx = ((size_t)(seq * 64 + g) * 512 + d0 + dl) * 16 + s;
    hend[idx] = h;
    Ag[idx] = P;
}

__global__ __launch_bounds__(256)
void scan2_k(float* __restrict__ hend, const float* __restrict__ Ag)
{
    int d = blockIdx.x * 16 + (threadIdx.x >> 4);
    int s = threadIdx.x & 15;
    int seq = blockIdx.y;
    float hin = 0.f;
    size_t base = ((size_t)seq * 64 * 512 + d) * 16 + s;
#pragma unroll 4
    for (int g = 0; g < 64; g++) {
        size_t idx = base + (size_t)g * 512 * 16;
        float he = hend[idx];
        float Av = Ag[idx];
        hend[idx] = hin;              // overwrite with incoming state
        hin = fmaf(Av, hin, he);
    }
}

__global__ __launch_bounds__(256)
void scan3_k(u16* __restrict__ xcv, const u16* __restrict__ zsil,
             const float* __restrict__ xdbl,
             const u16* __restrict__ dtW, const u16* __restrict__ dtB,
             const u16* __restrict__ A_log, const u16* __restrict__ D_skip,
             const float* __restrict__ hin)
{
    int d0 = blockIdx.x * 16;
    int g  = blockIdx.y;
    int seq = blockIdx.z;
    int tid = threadIdx.x;
    int s = tid & 15, dl = tid >> 4;
    float Aval = -__expf(bf2f(A_log[(d0 + dl) * 16 + s]));
    float Dv = bf2f(D_skip[d0 + dl]);

    __shared__ float dtlS[64][16], xS[64][16], zS[64][16], BS[64][16], CS[64][16];
    __shared__ float dtS[64][16], yS[64][16];
    __shared__ float WdS[16][16], bDS[16];
    {
        int r = tid & 15, dd = tid >> 4;
        WdS[dd][r] = bf2f(dtW[(d0 + dd) * 16 + r]);
        if (tid < 16) bDS[tid] = bf2f(dtB[d0 + tid]);
    }

    int ld_tt = tid >> 2;
    int ld_c4 = (tid & 3) * 4;
    int m0 = seq * 4096 + g * 64;
    {
        int m = m0 + ld_tt;
        const u16* px = xcv + (size_t)m * 512 + d0 + ld_c4;
        const u16* pz = zsil + (size_t)m * 512 + d0 + ld_c4;
#pragma unroll
        for (int r = 0; r < 4; r++) {
            xS[ld_tt][ld_c4 + r] = bf2f(px[r]);
            zS[ld_tt][ld_c4 + r] = bf2f(pz[r]);
        }
        const float* pl = xdbl + (size_t)m * 48;
#pragma unroll
        for (int r = 0; r < 4; r++) {
            dtlS[ld_tt][ld_c4 + r] = pl[ld_c4 + r];
            BS[ld_tt][ld_c4 + r]   = pl[16 + ld_c4 + r];
            CS[ld_tt][ld_c4 + r]   = pl[32 + ld_c4 + r];
        }
    }
    __syncthreads();
    {
        int tt = tid >> 2;
        int j0 = (tid & 3) * 4;
#pragma unroll
        for (int j = 0; j < 4; j++) {
            int dd = j0 + j;
            float a = bDS[dd];
#pragma unroll
            for (int r = 0; r < 16; r++) a = fmaf(dtlS[tt][r], WdS[dd][r], a);
            dtS[tt][dd] = (a > 20.f) ? a : log1pf(__expf(a));
        }
    }
    __syncthreads();

    float h = hin[((size_t)(seq * 64 + g) * 512 + d0 + dl) * 16 + s];
#pragma unroll 8
    for (int tt = 0; tt < 64; tt++) {
        float dtv = dtS[tt][dl];
        float xv  = xS[tt][dl];
        float a = __expf(dtv * Aval);
        h = fmaf(a, h, dtv * xv * BS[tt][s]);
        float yc = h * CS[tt][s];
        yc += __shfl_xor(yc, 1);
        yc += __shfl_xor(yc, 2);
        yc += __shfl_xor(yc, 4);
        yc += __shfl_xor(yc, 8);
        if (s == 0) yS[tt][dl] = (yc + Dv * xv) * zS[tt][dl];
    }
    __syncthreads();
    {
        int m = m0 + ld_tt;
        u16* py = xcv + (size_t)m * 512 + d0 + ld_c4;
        u32 a0 = (u32)f2bf(yS[ld_tt][ld_c4 + 0]) | ((u32)f2bf(yS[ld_tt][ld_c4 + 1]) << 16);
        u32 a1 = (u32)f2bf(yS[ld_tt][ld_c4 + 2]) | ((u32)f2bf(yS[ld_tt][ld_c4 + 3]) << 16);
        uint2 pk; pk.x = a0; pk.y = a1;
        *(uint2*)py = pk;
    }
}

// ---------------------------------------------------------------------------
// LayerNorm over combined fp32 accumulator
// ---------------------------------------------------------------------------
__global__ __launch_bounds__(256)
void ln_k(const float* __restrict__ accF, const u16* __restrict__ g,
          const u16* __restrict__ bt, u16* __restrict__ lnout)
{
    int m = blockIdx.x;
    int c = threadIdx.x;
    float v = accF[(size_t)m * 256 + c];

    float s1 = v, s2 = v * v;
#pragma unroll
    for (int o = 1; o < 64; o <<= 1) { s1 += __shfl_xor(s1, o); s2 += __shfl_xor(s2, o); }
    __shared__ float red[8];
    int wv = threadIdx.x >> 6;
    if ((threadIdx.x & 63) == 0) { red[wv] = s1; red[4 + wv] = s2; }
    __syncthreads();
    s1 = red[0] + red[1] + red[2] + red[3];
    s2 = red[4] + red[5] + red[6] + red[7];
    float mu = s1 * (1.f / 256.f);
    float var = s2 * (1.f / 256.f) - mu * mu;
    float rs = rsqrtf(fmaxf(var, 0.f) + 1e-5f);
    float o = (v - mu) * rs * bf2f(g[c]) + bf2f(bt[c]);
    lnout[(size_t)m * 256 + c] = f2bf(o);
}

// ---------------------------------------------------------------------------
extern "C" void kernel_launch(void* const* d_in, const int* in_sizes, int n_in,
                              void* d_out, int out_size, void* d_ws, size_t ws_size,
                              hipStream_t stream)
{
    char* w = (char*)d_ws;
    int* flag = (int*)w;
    size_t cur = 256;
    auto carve = [&](size_t bytes) { void* p = w + cur; cur = (cur + bytes + 255) & ~(size_t)255; return p; };

    static const int sizes[14] = {
        4194304, 262144, 2048, 512, 24576, 8192, 512, 8192, 512, 131072, 256, 256, 65536, 256
    };
    u16* cin[14];
    for (int i = 0; i < 14; i++) cin[i] = (u16*)carve((size_t)sizes[i] * 2);

    float* accF = (float*)carve(16777216);      // fp32 combine accumulator
    u16*  xcv  = (u16*)carve(16777216);         // per-direction xc/conv/y
    u16*  zbuf = (u16*)carve(16777216);         // per-direction silu(z)
    float* xdbl = (float*)carve(3145728);       // per-direction fp32 (dt_low|B|C)
    float* hend = (float*)carve(8388608);       // group end-state / incoming state
    float* Agp  = (float*)carve(8388608);       // group decay product
    u16*  lnb  = xcv;                           // reuse after last direction

    const u16* x          = cin[0];
    const u16* in_proj_w  = cin[1];
    const u16* conv_w     = cin[2];
    const u16* conv_b     = cin[3];
    const u16* x_proj_w   = cin[4];
    const u16* dt_proj_w  = cin[5];
    const u16* dt_proj_b  = cin[6];
    const u16* A_log      = cin[7];
    const u16* D_skip     = cin[8];
    const u16* mamba_out_w= cin[9];
    const u16* ln_g       = cin[10];
    const u16* ln_b       = cin[11];
    const u16* blk_out_w  = cin[12];
    const u16* blk_out_b  = cin[13];

    detect_k<<<dim3(1), 256, 0, stream>>>((const u16*)d_in[0], flag);
    for (int i = 0; i < 14; i++) {
        int n = sizes[i];
        int blocks = (n + 2047) / 2048; if (blocks < 1) blocks = 1;
        convert_k<<<dim3(blocks), 256, 0, stream>>>(d_in[i], cin[i], n, flag);
    }

    for (int dir = 0; dir < 4; dir++) {
        // 1. in_proj xc-half + conv + silu -> xcv
        gemmconv_k<<<dim3(8, 256), 256, 0, stream>>>(
            x, in_proj_w, conv_w, conv_b, xcv, dir);
        // 2. in_proj z-half + silu -> zbuf
        gemm_k<4, true><<<dim3(8, 256), 256, 0, stream>>>(
            x, in_proj_w + 512 * 256, TOKD, 512, 256, dir, nullptr, zbuf,
            nullptr, nullptr, nullptr);
        // 3. x_proj -> xdbl (fp32)
        gemm_k<1, false><<<dim3(1, 256), 256, 0, stream>>>(
            xcv, x_proj_w, TOKD, 48, 512, dir, xdbl, nullptr, nullptr, nullptr, nullptr);
        // 4. two-level selective scan (dt fused), gated y in place over xcv
        scan1_k<<<dim3(32, 64, 4), 256, 0, stream>>>(
            xcv, xdbl, dt_proj_w, dt_proj_b, A_log, hend, Agp);
        scan2_k<<<dim3(32, 4), 256, 0, stream>>>(hend, Agp);
        scan3_k<<<dim3(32, 64, 4), 256, 0, stream>>>(
            xcv, zbuf, xdbl, dt_proj_w, dt_proj_b, A_log, D_skip, hend);
        // 5. out projection, permuted rows into fp32 accumulator
        if (dir == 0)
            gemm_k<5, false><<<dim3(4, 256), 256, 0, stream>>>(
                xcv, mamba_out_w, TOKD, 256, 512, dir, accF, nullptr, nullptr, nullptr, nullptr);
        else
            gemm_k<6, false><<<dim3(4, 256), 256, 0, stream>>>(
                xcv, mamba_out_w, TOKD, 256, 512, dir, accF, nullptr, nullptr, nullptr, nullptr);
    }
    // 6. LayerNorm over combined accumulator
    ln_k<<<dim3(16384), 256, 0, stream>>>(accF, ln_g, ln_b, lnb);
    // 7. final projection + bias + residual (output dtype per flag)
    gemm_k<3, false><<<dim3(4, 256), 256, 0, stream>>>(
        lnb, blk_out_w, 16384, 256, 256, 0, (float*)d_out, (u16*)d_out,
        blk_out_b, x, flag);
}

// Round 6
// 1074.289 us; speedup vs baseline: 4.0058x; 1.3490x over previous
//
#include <hip/hip_runtime.h>

typedef unsigned short u16;
typedef unsigned int u32;
typedef __attribute__((ext_vector_type(8))) short short8;
typedef __attribute__((ext_vector_type(4))) float floatx4;
typedef __attribute__((ext_vector_type(4))) u32 uintx4;

#define LSEQ 4096
#define TOKD 16384            // tokens per direction (4 batches x 4096)

__device__ __forceinline__ float bf2f(u16 u) {
    u32 v = ((u32)u) << 16; float f; __builtin_memcpy(&f, &v, 4); return f;
}
__device__ __forceinline__ u16 f2bf(float f) {
    u32 v; __builtin_memcpy(&v, &f, 4);
    u32 r = v + 0x7fffu + ((v >> 16) & 1u);
    return (u16)(r >> 16);
}
__device__ __forceinline__ float siluf(float v) { return v / (1.f + __expf(-v)); }

// position in original image for token t of direction dir
__device__ __forceinline__ int dir_pos(int dir, int t) {
    if (dir == 0) return t;
    if (dir == 1) { int i = t >> 6, j = t & 63; return ((63 - j) << 6) | i; }
    if (dir == 2) return 4095 - t;
    int t2 = 4095 - t; int i = t2 >> 6, j = t2 & 63; return ((63 - j) << 6) | i;
}

// ---------------------------------------------------------------------------
// dtype detector (flag=1 -> fp32 inputs; confirmed fp32 in round 4)
// ---------------------------------------------------------------------------
__global__ __launch_bounds__(256)
void detect_k(const u16* __restrict__ xr, int* __restrict__ flag)
{
    int tid = threadIdx.x;
    int cnt = 0;
    for (int i = tid; i < 4096; i += 256) {
        float a = fabsf(bf2f(xr[i]));
        if (a > 0.001f && a < 100.f) cnt++;
    }
#pragma unroll
    for (int o = 1; o < 64; o <<= 1) cnt += __shfl_xor(cnt, o);
    __shared__ int red[4];
    if ((tid & 63) == 0) red[tid >> 6] = cnt;
    __syncthreads();
    if (tid == 0) flag[0] = ((red[0] + red[1] + red[2] + red[3]) < 3277) ? 1 : 0;
}

__global__ __launch_bounds__(256)
void convert_k(const void* __restrict__ src, u16* __restrict__ dst, int n,
               const int* __restrict__ flag)
{
    bool isf = flag[0] != 0;
    int stride = gridDim.x * 256;
    for (int i = blockIdx.x * 256 + threadIdx.x; i < n; i += stride) {
        dst[i] = isf ? f2bf(((const float*)src)[i]) : ((const u16*)src)[i];
    }
}

// ---------------------------------------------------------------------------
// bf16 MFMA GEMM core: C(M,N) = A(M,K) @ Bw(N,K)^T, tile 64x64, 256 thr.
// EPI: 1 = fp32 store w/ col guard (x_proj N=48)
//      3 = store + bias + residual (final; fp32 or bf16 per flag)
//      4 = bf16 store of silu(v)   (z half)
//      5 = fp32 STORE to permuted row (out-proj, dir 0)
//      6 = fp32 ADD   to permuted row (out-proj, dirs 1-3)
// ---------------------------------------------------------------------------
template<int EPI, bool GATHER>
__global__ __launch_bounds__(256)
void gemm_k(const u16* __restrict__ A, const u16* __restrict__ Bw,
            int M, int N, int K, int dir,
            float* __restrict__ outF, u16* __restrict__ out0,
            const u16* __restrict__ bias, const u16* __restrict__ resid,
            const int* __restrict__ flag)
{
    __shared__ __align__(16) u16 As[64][40];
    __shared__ __align__(16) u16 Bs[64][40];

    int tid = threadIdx.x;
    int ntile = blockIdx.x, mtile = blockIdx.y;
    int lr = tid >> 2;
    int lc = (tid & 3) << 3;

    const u16* arow;
    {
        int g = mtile * 64 + lr;
        if (GATHER) {
            int b = g >> 12, t = g & 4095;
            arow = A + (size_t)(b * 4096 + dir_pos(dir, t)) * K;
        } else {
            arow = A + (size_t)g * K;
        }
    }
    int bn = ntile * 64 + lr;
    const u16* brow = (bn < N) ? (Bw + (size_t)bn * K) : nullptr;

    floatx4 acc[4];
#pragma unroll
    for (int i = 0; i < 4; i++) acc[i] = (floatx4)0.f;

    int lane = tid & 63, wv = tid >> 6;
    int lm = lane & 15;
    int kq = (lane >> 4) << 3;

    for (int k0 = 0; k0 < K; k0 += 32) {
        __syncthreads();
        uintx4 av = *(const uintx4*)(arow + k0 + lc);
        uintx4 bv = {0u, 0u, 0u, 0u};
        if (brow) bv = *(const uintx4*)(brow + k0 + lc);
        *(uintx4*)(&As[lr][lc]) = av;
        *(uintx4*)(&Bs[lr][lc]) = bv;
        __syncthreads();
        short8 af = *(const short8*)(&As[wv * 16 + lm][kq]);
#pragma unroll
        for (int nt = 0; nt < 4; nt++) {
            short8 bf = *(const short8*)(&Bs[nt * 16 + lm][kq]);
            acc[nt] = __builtin_amdgcn_mfma_f32_16x16x32_bf16(af, bf, acc[nt], 0, 0, 0);
        }
    }

    bool isf = (EPI == 3) ? (flag[0] != 0) : false;
    int colb = lane & 15;
    int rowb = (lane >> 4) << 2;
#pragma unroll
    for (int nt = 0; nt < 4; nt++) {
#pragma unroll
        for (int r = 0; r < 4; r++) {
            int mg = mtile * 64 + wv * 16 + rowb + r;
            int cg = ntile * 64 + nt * 16 + colb;
            float v = acc[nt][r];
            if (EPI == 1) {
                if (cg < N) outF[(size_t)mg * N + cg] = v;
            } else if (EPI == 3) {
                size_t idx = (size_t)mg * N + cg;
                float rr = v + bf2f(bias[cg]) + bf2f(resid[idx]);
                if (isf) outF[idx] = rr;
                else     out0[idx] = f2bf(rr);
            } else if (EPI == 4) {
                out0[(size_t)mg * N + cg] = f2bf(siluf(v));
            } else {
                int b = mg >> 12, t = mg & 4095;
                size_t idx = (size_t)(b * 4096 + dir_pos(dir, t)) * N + cg;
                if (EPI == 5) outF[idx] = v;
                else          outF[idx] += v;
            }
        }
    }
}

// ---------------------------------------------------------------------------
// fused in_proj(xc half) GEMM + depthwise causal conv(k=4) + bias + SiLU.
// ---------------------------------------------------------------------------
__global__ __launch_bounds__(256)
void gemmconv_k(const u16* __restrict__ x, const u16* __restrict__ Wc,
                const u16* __restrict__ cw, const u16* __restrict__ cb,
                u16* __restrict__ xcv, int dir)
{
    __shared__ __align__(16) u16 As[64][40];
    __shared__ __align__(16) u16 Bs[64][40];
    __shared__ float xcS[67][68];

    int tid = threadIdx.x;
    int ntile = blockIdx.x, mtile = blockIdx.y;
    int n0 = ntile * 64;
    int g0 = mtile * 64;
    int bb = g0 >> 12;
    int lr = tid >> 2;
    int lc = (tid & 3) << 3;

    const u16* arow = x + (size_t)(bb * 4096 + dir_pos(dir, (g0 + lr) & 4095)) * 256;
    const u16* brow = Wc + (size_t)(n0 + lr) * 256;

    floatx4 acc[4];
#pragma unroll
    for (int i = 0; i < 4; i++) acc[i] = (floatx4)0.f;

    int lane = tid & 63, wv = tid >> 6;
    int lm = lane & 15;
    int kq = (lane >> 4) << 3;

    for (int k0 = 0; k0 < 256; k0 += 32) {
        __syncthreads();
        uintx4 av = *(const uintx4*)(arow + k0 + lc);
        uintx4 bv = *(const uintx4*)(brow + k0 + lc);
        *(uintx4*)(&As[lr][lc]) = av;
        *(uintx4*)(&Bs[lr][lc]) = bv;
        __syncthreads();
        short8 af = *(const short8*)(&As[wv * 16 + lm][kq]);
#pragma unroll
        for (int nt = 0; nt < 4; nt++) {
            short8 bf = *(const short8*)(&Bs[nt * 16 + lm][kq]);
            acc[nt] = __builtin_amdgcn_mfma_f32_16x16x32_bf16(af, bf, acc[nt], 0, 0, 0);
        }
    }

    __syncthreads();
    {
        int colb = lane & 15;
        int rowb = (lane >> 4) << 2;
#pragma unroll
        for (int nt = 0; nt < 4; nt++)
#pragma unroll
            for (int r = 0; r < 4; r++)
                xcS[3 + wv * 16 + rowb + r][nt * 16 + colb] = acc[nt][r];
    }
    if (tid < 192) {
        int hr = tid >> 6, hc = tid & 63;
        int th = (g0 & 4095) - 3 + hr;
        float a = 0.f;
        if (th >= 0) {
            const u16* xr = x + (size_t)(bb * 4096 + dir_pos(dir, th)) * 256;
            const u16* wr = Wc + (size_t)(n0 + hc) * 256;
            for (int k = 0; k < 256; k += 8) {
                uintx4 xv = *(const uintx4*)(xr + k);
                uintx4 wv4 = *(const uintx4*)(wr + k);
                const u16* pxv = (const u16*)&xv;
                const u16* pwv = (const u16*)&wv4;
#pragma unroll
                for (int i = 0; i < 8; i++) a += bf2f(pxv[i]) * bf2f(pwv[i]);
            }
        }
        xcS[hr][hc] = a;
    }
    __syncthreads();
    for (int e = tid; e < 4096; e += 256) {
        int tr = e >> 6, c = e & 63;
        float s = bf2f(cb[n0 + c]);
#pragma unroll
        for (int k = 0; k < 4; k++)
            s += bf2f(cw[(n0 + c) * 4 + k]) * xcS[tr + k][c];
        xcv[(size_t)(g0 + tr) * 512 + n0 + c] = f2bf(siluf(s));
    }
}

// ---------------------------------------------------------------------------
// dt = softplus(dt_low @ Wd^T + b) for all tokens -> dtb (bf16 TOKD x 512).
// grid (8 d-blocks, 256 token-blocks); hoisted out of the scan kernels.
// ---------------------------------------------------------------------------
__global__ __launch_bounds__(256)
void dt_k(const float* __restrict__ xdbl, const u16* __restrict__ dtW,
          const u16* __restrict__ dtB, u16* __restrict__ dtb)
{
    int n0 = blockIdx.x * 64;
    int m0 = blockIdx.y * 64;
    __shared__ __align__(16) float dtl[64][16];
    __shared__ __align__(16) u16 Wds[64][16];
    __shared__ float bDs[64];

    int tid = threadIdx.x;
    int t = tid >> 2, q = tid & 3;
    *(floatx4*)&dtl[t][q * 4] = *(const floatx4*)(xdbl + (size_t)(m0 + t) * 48 + q * 4);
    *(uint2*)&Wds[t][q * 4] = *(const uint2*)(dtW + (size_t)(n0 + t) * 16 + q * 4);
    if (tid < 64) bDs[tid] = bf2f(dtB[n0 + tid]);
    __syncthreads();

    floatx4 lv[4];
#pragma unroll
    for (int i = 0; i < 4; i++) lv[i] = *(floatx4*)&dtl[t][i * 4];

    u16 ores[16];
#pragma unroll
    for (int dd = 0; dd < 16; dd++) {
        int d = q * 16 + dd;
        short8 w0 = *(short8*)&Wds[d][0];
        short8 w1 = *(short8*)&Wds[d][8];
        float a = bDs[d];
#pragma unroll
        for (int r = 0; r < 8; r++) a = fmaf(lv[r >> 2][r & 3], bf2f((u16)w0[r]), a);
#pragma unroll
        for (int r = 0; r < 8; r++) a = fmaf(lv[(r + 8) >> 2][r & 3], bf2f((u16)w1[r]), a);
        float sp = (a > 20.f) ? a : log1pf(__expf(a));
        ores[dd] = f2bf(sp);
    }
    u16* po = dtb + (size_t)(m0 + t) * 512 + n0 + q * 16;
    *(uintx4*)po = *(uintx4*)&ores[0];
    *(uintx4*)(po + 8) = *(uintx4*)&ores[8];
}

// ===========================================================================
// Two-level chunked scan, LDS-lean version: transposed [ch][t] staging with
// b128 strip reads; dt precomputed (dt_k). Thread (s = tid&15, dl = tid>>4);
// wave w owns channels 4w..4w+3, so the y-reduce stays in-wave (no barrier).
// ===========================================================================
__global__ __launch_bounds__(256)
void scan1_k(const u16* __restrict__ xcv, const u16* __restrict__ dtb,
             const float* __restrict__ xdbl, const u16* __restrict__ A_log,
             float* __restrict__ hend, float* __restrict__ Ag)
{
    int d0 = blockIdx.x * 16;
    int g  = blockIdx.y;
    int seq = blockIdx.z;
    int m0 = seq * 4096 + g * 64;
    int tid = threadIdx.x;
    int s = tid & 15, dl = tid >> 4;
    float Aval = -__expf(bf2f(A_log[(d0 + dl) * 16 + s]));

    __shared__ __align__(16) u16 dtT[16][80];
    __shared__ __align__(16) u16 xT[16][80];
    __shared__ __align__(16) float BT[16][76];

    {   // transposed staging
        int tt = tid >> 2, c4 = (tid & 3) * 4;
        uint2 xv = *(const uint2*)(xcv + (size_t)(m0 + tt) * 512 + d0 + c4);
        uint2 dv = *(const uint2*)(dtb + (size_t)(m0 + tt) * 512 + d0 + c4);
        const u16* px = (const u16*)&xv;
        const u16* pd = (const u16*)&dv;
        floatx4 bv = *(const floatx4*)(xdbl + (size_t)(m0 + tt) * 48 + 16 + c4);
#pragma unroll
        for (int r = 0; r < 4; r++) {
            xT[c4 + r][tt] = px[r];
            dtT[c4 + r][tt] = pd[r];
            BT[c4 + r][tt] = bv[r];
        }
    }
    __syncthreads();

    float h = 0.f, S = 0.f;
    for (int t0 = 0; t0 < 64; t0 += 8) {
        short8 d8 = *(const short8*)&dtT[dl][t0];
        short8 x8 = *(const short8*)&xT[dl][t0];
        floatx4 b0 = *(const floatx4*)&BT[s][t0];
        floatx4 b1 = *(const floatx4*)&BT[s][t0 + 4];
#pragma unroll
        for (int t = 0; t < 8; t++) {
            float dtv = bf2f((u16)d8[t]);
            float Bv = (t < 4) ? b0[t & 3] : b1[t & 3];
            float a = __expf(dtv * Aval);
            h = fmaf(a, h, dtv * bf2f((u16)x8[t]) * Bv);
            S += dtv;
        }
    }
    size_t idx = ((size_t)(seq * 64 + g) * 512 + d0 + dl) * 16 + s;
    hend[idx] = h;
    Ag[idx] = __expf(Aval * S);
}

__global__ __launch_bounds__(256)
void scan2_k(float* __restrict__ hend, const float* __restrict__ Ag)
{
    int d = blockIdx.x * 16 + (threadIdx.x >> 4);
    int s = threadIdx.x & 15;
    int seq = blockIdx.y;
    float hin = 0.f;
    size_t base = ((size_t)seq * 64 * 512 + d) * 16 + s;
#pragma unroll 4
    for (int g = 0; g < 64; g++) {
        size_t idx = base + (size_t)g * 512 * 16;
        float he = hend[idx];
        float Av = Ag[idx];
        hend[idx] = hin;
        hin = fmaf(Av, hin, he);
    }
}

__global__ __launch_bounds__(256)
void scan3_k(u16* __restrict__ xcv, const u16* __restrict__ zsil,
             const u16* __restrict__ dtb, const float* __restrict__ xdbl,
             const u16* __restrict__ A_log, const u16* __restrict__ D_skip,
             const float* __restrict__ hin)
{
    int d0 = blockIdx.x * 16;
    int g  = blockIdx.y;
    int seq = blockIdx.z;
    int m0 = seq * 4096 + g * 64;
    int tid = threadIdx.x;
    int s = tid & 15, dl = tid >> 4;
    int w = tid >> 6, l = tid & 63;
    float Aval = -__expf(bf2f(A_log[(d0 + dl) * 16 + s]));

    // reduce-role (lanes l<32 of each wave): rdl in this wave's channel quad
    int rdl = (w << 2) | (l & 3);
    int rt = (l >> 2) & 7;
    float Dv_r = bf2f(D_skip[d0 + rdl]);

    __shared__ __align__(16) u16 dtT[16][80];
    __shared__ __align__(16) u16 xT[16][80];
    __shared__ __align__(16) u16 zT[16][80];
    __shared__ __align__(16) float BT[16][76];
    __shared__ __align__(16) float CT[16][76];
    __shared__ __align__(16) float yPf[2624];   // [dl]*164 + [t]*20 + [s]

    {   // transposed staging
        int tt = tid >> 2, c4 = (tid & 3) * 4;
        uint2 xv = *(const uint2*)(xcv + (size_t)(m0 + tt) * 512 + d0 + c4);
        uint2 zv = *(const uint2*)(zsil + (size_t)(m0 + tt) * 512 + d0 + c4);
        uint2 dv = *(const uint2*)(dtb + (size_t)(m0 + tt) * 512 + d0 + c4);
        const u16* px = (const u16*)&xv;
        const u16* pz = (const u16*)&zv;
        const u16* pd = (const u16*)&dv;
        floatx4 bv = *(const floatx4*)(xdbl + (size_t)(m0 + tt) * 48 + 16 + c4);
        floatx4 cv = *(const floatx4*)(xdbl + (size_t)(m0 + tt) * 48 + 32 + c4);
#pragma unroll
        for (int r = 0; r < 4; r++) {
            xT[c4 + r][tt] = px[r];
            zT[c4 + r][tt] = pz[r];
            dtT[c4 + r][tt] = pd[r];
            BT[c4 + r][tt] = bv[r];
            CT[c4 + r][tt] = cv[r];
        }
    }
    __syncthreads();

    float h = hin[((size_t)(seq * 64 + g) * 512 + d0 + dl) * 16 + s];

    for (int t0 = 0; t0 < 64; t0 += 8) {
        short8 d8 = *(const short8*)&dtT[dl][t0];
        short8 x8 = *(const short8*)&xT[dl][t0];
        floatx4 b0 = *(const floatx4*)&BT[s][t0];
        floatx4 b1 = *(const floatx4*)&BT[s][t0 + 4];
        floatx4 c0 = *(const floatx4*)&CT[s][t0];
        floatx4 c1 = *(const floatx4*)&CT[s][t0 + 4];
#pragma unroll
        for (int t = 0; t < 8; t++) {
            float dtv = bf2f((u16)d8[t]);
            float xv  = bf2f((u16)x8[t]);
            float Bv = (t < 4) ? b0[t & 3] : b1[t & 3];
            float Cv = (t < 4) ? c0[t & 3] : c1[t & 3];
            float a = __expf(dtv * Aval);
            h = fmaf(a, h, dtv * xv * Bv);
            yPf[dl * 164 + t * 20 + s] = h * Cv;
        }
        __builtin_amdgcn_wave_barrier();
        if (l < 32) {   // in-wave reduce over 16 states (LDS in-order per wave)
            int base = rdl * 164 + rt * 20;
            floatx4 y0 = *(const floatx4*)&yPf[base];
            floatx4 y1 = *(const floatx4*)&yPf[base + 4];
            floatx4 y2 = *(const floatx4*)&yPf[base + 8];
            floatx4 y3 = *(const floatx4*)&yPf[base + 12];
            float sum = (y0[0] + y0[1] + y0[2] + y0[3]) + (y1[0] + y1[1] + y1[2] + y1[3])
                      + (y2[0] + y2[1] + y2[2] + y2[3]) + (y3[0] + y3[1] + y3[2] + y3[3]);
            float xr = bf2f(xT[rdl][t0 + rt]);
            float zr = bf2f(zT[rdl][t0 + rt]);
            float yfin = (sum + Dv_r * xr) * zr;
            xcv[(size_t)(m0 + t0 + rt) * 512 + d0 + rdl] = f2bf(yfin);
        }
        __builtin_amdgcn_wave_barrier();
    }
}

// ---------------------------------------------------------------------------
// LayerNorm over combined fp32 accumulator
// ---------------------------------------------------------------------------
__global__ __launch_bounds__(256)
void ln_k(const float* __restrict__ accF, const u16* __restrict__ g,
          const u16* __restrict__ bt, u16* __restrict__ lnout)
{
    int m = blockIdx.x;
    int c = threadIdx.x;
    float v = accF[(size_t)m * 256 + c];

    float s1 = v, s2 = v * v;
#pragma unroll
    for (int o = 1; o < 64; o <<= 1) { s1 += __shfl_xor(s1, o); s2 += __shfl_xor(s2, o); }
    __shared__ float red[8];
    int wv = threadIdx.x >> 6;
    if ((threadIdx.x & 63) == 0) { red[wv] = s1; red[4 + wv] = s2; }
    __syncthreads();
    s1 = red[0] + red[1] + red[2] + red[3];
    s2 = red[4] + red[5] + red[6] + red[7];
    float mu = s1 * (1.f / 256.f);
    float var = s2 * (1.f / 256.f) - mu * mu;
    float rs = rsqrtf(fmaxf(var, 0.f) + 1e-5f);
    float o = (v - mu) * rs * bf2f(g[c]) + bf2f(bt[c]);
    lnout[(size_t)m * 256 + c] = f2bf(o);
}

// ---------------------------------------------------------------------------
extern "C" void kernel_launch(void* const* d_in, const int* in_sizes, int n_in,
                              void* d_out, int out_size, void* d_ws, size_t ws_size,
                              hipStream_t stream)
{
    char* w = (char*)d_ws;
    int* flag = (int*)w;
    size_t cur = 256;
    auto carve = [&](size_t bytes) { void* p = w + cur; cur = (cur + bytes + 255) & ~(size_t)255; return p; };

    static const int sizes[14] = {
        4194304, 262144, 2048, 512, 24576, 8192, 512, 8192, 512, 131072, 256, 256, 65536, 256
    };
    u16* cin[14];
    for (int i = 0; i < 14; i++) cin[i] = (u16*)carve((size_t)sizes[i] * 2);

    float* accF = (float*)carve(16777216);      // fp32 combine accumulator
    u16*  xcv  = (u16*)carve(16777216);         // per-direction xc/conv/y
    u16*  zbuf = (u16*)carve(16777216);         // per-direction silu(z)
    float* xdbl = (float*)carve(3145728);       // per-direction fp32 (dt_low|B|C)
    float* hend = (float*)carve(8388608);       // group end-state / incoming state
    float* Agp  = (float*)carve(8388608);       // group decay product
    u16*  dtb  = (u16*)carve(16777216);         // per-direction dt (bf16)
    u16*  lnb  = xcv;                           // reuse after last direction

    const u16* x          = cin[0];
    const u16* in_proj_w  = cin[1];
    const u16* conv_w     = cin[2];
    const u16* conv_b     = cin[3];
    const u16* x_proj_w   = cin[4];
    const u16* dt_proj_w  = cin[5];
    const u16* dt_proj_b  = cin[6];
    const u16* A_log      = cin[7];
    const u16* D_skip     = cin[8];
    const u16* mamba_out_w= cin[9];
    const u16* ln_g       = cin[10];
    const u16* ln_b       = cin[11];
    const u16* blk_out_w  = cin[12];
    const u16* blk_out_b  = cin[13];

    detect_k<<<dim3(1), 256, 0, stream>>>((const u16*)d_in[0], flag);
    for (int i = 0; i < 14; i++) {
        int n = sizes[i];
        int blocks = (n + 2047) / 2048; if (blocks < 1) blocks = 1;
        convert_k<<<dim3(blocks), 256, 0, stream>>>(d_in[i], cin[i], n, flag);
    }

    for (int dir = 0; dir < 4; dir++) {
        // 1. in_proj xc-half + conv + silu -> xcv
        gemmconv_k<<<dim3(8, 256), 256, 0, stream>>>(
            x, in_proj_w, conv_w, conv_b, xcv, dir);
        // 2. in_proj z-half + silu -> zbuf
        gemm_k<4, true><<<dim3(8, 256), 256, 0, stream>>>(
            x, in_proj_w + 512 * 256, TOKD, 512, 256, dir, nullptr, zbuf,
            nullptr, nullptr, nullptr);
        // 3. x_proj -> xdbl (fp32)
        gemm_k<1, false><<<dim3(1, 256), 256, 0, stream>>>(
            xcv, x_proj_w, TOKD, 48, 512, dir, xdbl, nullptr, nullptr, nullptr, nullptr);
        // 4. dt projection + softplus -> dtb (bf16)
        dt_k<<<dim3(8, 256), 256, 0, stream>>>(xdbl, dt_proj_w, dt_proj_b, dtb);
        // 5. two-level selective scan, gated y in place over xcv
        scan1_k<<<dim3(32, 64, 4), 256, 0, stream>>>(
            xcv, dtb, xdbl, A_log, hend, Agp);
        scan2_k<<<dim3(32, 4), 256, 0, stream>>>(hend, Agp);
        scan3_k<<<dim3(32, 64, 4), 256, 0, stream>>>(
            xcv, zbuf, dtb, xdbl, A_log, D_skip, hend);
        // 6. out projection, permuted rows into fp32 accumulator
        if (dir == 0)
            gemm_k<5, false><<<dim3(4, 256), 256, 0, stream>>>(
                xcv, mamba_out_w, TOKD, 256, 512, dir, accF, nullptr, nullptr, nullptr, nullptr);
        else
            gemm_k<6, false><<<dim3(4, 256), 256, 0, stream>>>(
                xcv, mamba_out_w, TOKD, 256, 512, dir, accF, nullptr, nullptr, nullptr, nullptr);
    }
    // 7. LayerNorm over combined accumulator
    ln_k<<<dim3(16384), 256, 0, stream>>>(accF, ln_g, ln_b, lnb);
    // 8. final projection + bias + residual (output dtype per flag)
    gemm_k<3, false><<<dim3(4, 256), 256, 0, stream>>>(
        lnb, blk_out_w, 16384, 256, 256, 0, (float*)d_out, (u16*)d_out,
        blk_out_b, x, flag);
}